// Round 3
// baseline (202.298 us; speedup 1.0000x reference)
//
#include <hip/hip_runtime.h>
#include <hip/hip_bf16.h>

// B=2, N=2048, D=1024, H=16, DH=64. Output fp32; inputs runtime-detected and
// converted once. R12: (a) qkv/oproj staging via global_load_lds width=16
// (m97 ladder step) with XOR chunk swizzle (store c^((r>>1)&3)) replacing
// padding; (b) attn diagonal-tile specialization (branch-free main subtiles).
// R14: attn ALiBi reach cap (sl2*j>46 tiles skipped; 0.54x work).
// R15: attn was CRITICAL-PATH bound (47.9us/32 tiles = 1.5us/tile serial
// chain; utilization counters all fell after R14 cap). Split each (bh,qb)
// item's j-range 4-ways inside a 1024-thread block: 4 groups x 256 thr,
// private 18KB K/V LDS each (72KB total, 2 blocks/CU = 32 waves/CU), final
// in-LDS merge of partial accv/accl (linear, exact). Critical path 32 -> 8
// tiles; tail runs 4 waves/SIMD instead of 1.
//
// ws (bf16 elems): Q@0(4M), K@4M, Vt@8M, Xc/AO@12M (shared), WqT@16M..WoT@19M,
// boc@20M. ~40MB.

typedef __bf16 bf16x8 __attribute__((ext_vector_type(8)));
typedef float f32x4 __attribute__((ext_vector_type(4)));
typedef short s4 __attribute__((ext_vector_type(4)));      // k16 MFMA A/B frag
typedef unsigned short ushort_t;

#define MFMA_16x16x32(a, b, c) __builtin_amdgcn_mfma_f32_16x16x32_bf16(a, b, c, 0, 0, 0)
#define MFMA16(a, b, c) __builtin_amdgcn_mfma_f32_16x16x16bf16_1k(a, b, c, 0, 0, 0)

__device__ __forceinline__ ushort_t f2bf(float f) {
    __hip_bfloat16 h = __float2bfloat16(f);
    return __builtin_bit_cast(ushort_t, h);
}
__device__ __forceinline__ float bf2f(ushort_t u) {
    unsigned x = ((unsigned)u) << 16;
    return __builtin_bit_cast(float, x);
}

// async global->LDS, 16B/lane; LDS dest = wave-uniform base + lane*16.
__device__ __forceinline__ void gl_lds16(const ushort_t* g, ushort_t* l) {
    __builtin_amdgcn_global_load_lds(
        (const __attribute__((address_space(1))) void*)g,
        (__attribute__((address_space(3))) void*)l, 16, 0, 0);
}

__device__ __forceinline__ unsigned detect_fp32(const void* wp) {
    const ushort_t* w = (const ushort_t*)wp;
    unsigned c = 0;
    #pragma unroll
    for (int i = 0; i < 128; ++i) c += (((w[i] >> 7) & 0xFF) >= 0x7F) ? 1u : 0u;
    return (c > 8) ? 1u : 0u;
}

__device__ __forceinline__ uint4 load8(const void* p, size_t idx, unsigned flag) {
    if (flag) {
        const float* f = (const float*)p + idx;
        float4 a = *(const float4*)f;
        float4 b = *(const float4*)(f + 4);
        ushort_t u[8] = { f2bf(a.x), f2bf(a.y), f2bf(a.z), f2bf(a.w),
                          f2bf(b.x), f2bf(b.y), f2bf(b.z), f2bf(b.w) };
        return *(uint4*)u;
    }
    return *(const uint4*)((const ushort_t*)p + idx);
}

// ---------------- convert X + bias ----------------
__global__ __launch_bounds__(256) void convert_x(
    const void* __restrict__ X, const void* __restrict__ Wq, const void* __restrict__ bo,
    ushort_t* __restrict__ Xc, ushort_t* __restrict__ boc)
{
    const unsigned flag = detect_fp32(Wq);
    const int blk = blockIdx.x;
    if (blk < 2048) {
        size_t idx = (size_t)blk * 2048 + (size_t)threadIdx.x * 8;
        *(uint4*)(Xc + idx) = load8(X, idx, flag);
    } else {
        size_t idx = (size_t)threadIdx.x * 8;
        if (idx < 1024) *(uint4*)(boc + idx) = load8(bo, idx, flag);
    }
}

// ---------------- transpose weights -> WT[n][k] ----------------
__global__ __launch_bounds__(256) void transpose_w(
    const void* __restrict__ Wq, const void* __restrict__ Wk,
    const void* __restrict__ Wv, const void* __restrict__ Wo,
    ushort_t* __restrict__ WqT, ushort_t* __restrict__ WkT,
    ushort_t* __restrict__ WvT, ushort_t* __restrict__ WoT)
{
    __shared__ ushort_t T[64][72];
    const unsigned flag = detect_fp32(Wq);
    const int z = blockIdx.z;
    const void* W = (z == 0) ? Wq : ((z == 1) ? Wk : ((z == 2) ? Wv : Wo));
    ushort_t* WT = (z == 0) ? WqT : ((z == 1) ? WkT : ((z == 2) ? WvT : WoT));

    const int k0 = blockIdx.y * 64, n0 = blockIdx.x * 64;
    const int r = threadIdx.x >> 2, c = (threadIdx.x & 3) * 16;

    *(uint4*)&T[r][c]     = load8(W, (size_t)(k0 + r) * 1024 + n0 + c,     flag);
    *(uint4*)&T[r][c + 8] = load8(W, (size_t)(k0 + r) * 1024 + n0 + c + 8, flag);
    __syncthreads();
    ushort_t tmp[16];
    #pragma unroll
    for (int j = 0; j < 16; ++j) tmp[j] = T[c + j][r];
    *(uint4*)(WT + (size_t)(n0 + r) * 1024 + k0 + c)     = *(uint4*)&tmp[0];
    *(uint4*)(WT + (size_t)(n0 + r) * 1024 + k0 + c + 8) = *(uint4*)&tmp[8];
}

// ---------------- QKV projection GEMM, 128x128, global_load_lds staging ----------------
// grid (8, 32, 3), block 256 (4 waves), BK=32. Unpadded LDS 128x32 shorts.
// Swizzle: LDS (row r, chunk c) holds global k-chunk c^((r>>1)&3).
// Store side: lane l writes chunk l&3 of row (t*64+wv*16+(l>>2)) -> source
// chunk (l&3)^((l>>3)&3). Read side: row R=wm+t*16+l15 chunk q at position
// q^((l15>>1)&3). Conflict-free (8 dwords/bank = b128 minimum).
__global__ __launch_bounds__(256) void qkv_gemm(
    const ushort_t* __restrict__ X, const ushort_t* __restrict__ WqT,
    const ushort_t* __restrict__ WkT, const ushort_t* __restrict__ WvT,
    ushort_t* __restrict__ Q, ushort_t* __restrict__ K, ushort_t* __restrict__ Vt)
{
    __shared__ ushort_t As[128 * 32];
    __shared__ ushort_t Bs[128 * 32];

    const int z = blockIdx.z;
    const ushort_t* WT = (z == 0) ? WqT : ((z == 1) ? WkT : WvT);

    const int tid  = threadIdx.x;
    const int m0   = blockIdx.y * 128, n0 = blockIdx.x * 128;
    const int lane = tid & 63, wv = tid >> 6;
    const int quad = lane >> 4, l15 = lane & 15;
    const int wm = (wv & 1) * 64, wn = (wv >> 1) * 64;

    const int lrow = lane >> 2;                         // 0..15
    const int schk = (lane & 3) ^ ((lane >> 3) & 3);    // swizzled source chunk
    const int ra0_ = wv * 16 + lrow;                    // issue-0 row
    ushort_t* aB0 = As + wv * 512;                      // wave-uniform LDS bases
    ushort_t* aB1 = As + 2048 + wv * 512;
    ushort_t* bB0 = Bs + wv * 512;
    ushort_t* bB1 = Bs + 2048 + wv * 512;
    const int sp = quad ^ ((l15 >> 1) & 3);             // read chunk position

    f32x4 acc[4][4] = {};

    for (int kt = 0; kt < 32; ++kt) {
        const int k0 = kt * 32;
        __syncthreads();
        gl_lds16(X  + (size_t)(m0 + ra0_)      * 1024 + k0 + schk * 8, aB0);
        gl_lds16(X  + (size_t)(m0 + 64 + ra0_) * 1024 + k0 + schk * 8, aB1);
        gl_lds16(WT + (size_t)(n0 + ra0_)      * 1024 + k0 + schk * 8, bB0);
        gl_lds16(WT + (size_t)(n0 + 64 + ra0_) * 1024 + k0 + schk * 8, bB1);
        __syncthreads();   // compiler emits vmcnt(0) drain -> LDS data visible

        bf16x8 af[4], bfr[4];
        #pragma unroll
        for (int t = 0; t < 4; ++t) {
            af[t]  = *(const bf16x8*)(As + (wm + t * 16 + l15) * 32 + sp * 8);
            bfr[t] = *(const bf16x8*)(Bs + (wn + t * 16 + l15) * 32 + sp * 8);
        }
        #pragma unroll
        for (int mt = 0; mt < 4; ++mt)
            #pragma unroll
            for (int nt = 0; nt < 4; ++nt)
                acc[mt][nt] = MFMA_16x16x32(af[mt], bfr[nt], acc[mt][nt]);
    }

    #pragma unroll
    for (int mt = 0; mt < 4; ++mt) {
        #pragma unroll
        for (int nt = 0; nt < 4; ++nt) {
            if (z == 2) {
                int c  = n0 + wn + nt * 16 + l15;
                int h  = c >> 6, dh = c & 63;
                int mA = m0 + wm + mt * 16 + quad * 4;
                int b  = mA >> 11, nseq = mA & 2047;
                ushort_t pk[4];
                #pragma unroll
                for (int r = 0; r < 4; ++r) pk[r] = f2bf(acc[mt][nt][r]);
                *(ushort2*)(Vt + ((size_t)((b * 16 + h) * 64 + dh)) * 2048 + nseq)     = *(ushort2*)&pk[0];
                *(ushort2*)(Vt + ((size_t)((b * 16 + h) * 64 + dh)) * 2048 + nseq + 2) = *(ushort2*)&pk[2];
            } else {
                ushort_t* dst = (z == 0) ? Q : K;
                #pragma unroll
                for (int r = 0; r < 4; ++r) {
                    int m = m0 + wm + mt * 16 + quad * 4 + r;
                    int c = n0 + wn + nt * 16 + l15;
                    int b = m >> 11, nseq = m & 2047;
                    int h = c >> 6, dh = c & 63;
                    dst[((size_t)((b * 16 + h) * 2048 + nseq)) * 64 + dh] = f2bf(acc[mt][nt][r]);
                }
            }
        }
    }
}

// ---------------- MFMA flash attention: 4-group split-j + in-LDS merge ----------------
// grid (32 bh, 32 q-blocks), block 1024 = 4 groups x 4 waves, qb = 31-y (LPT).
// Group g handles contiguous j-tiles [g*iters, min(ntiles,(g+1)*iters)) in its
// private 18KB K/V LDS region; iters = ceil(ntiles/4) is block-uniform so all
// groups hit the same barrier count. Partial accv/accl merged through LDS
// (reused K/V area, 68KB) -- softmax partial sums are linear, merge is exact.
__global__ __launch_bounds__(1024) void attn_kernel(
    const ushort_t* __restrict__ Q, const ushort_t* __restrict__ K,
    const ushort_t* __restrict__ Vt, ushort_t* __restrict__ AO)
{
    __shared__ ushort_t SM[4 * 9216];  // per group: Ks 64*72 + Vs 64*72 shorts

    const int tid  = threadIdx.x;
    const int grp  = tid >> 8;          // 0..3 j-chunk group
    const int ltid = tid & 255;
    const int wv   = ltid >> 6, lane = ltid & 63;
    const int quad = lane >> 4, l15 = lane & 15;
    const int bh   = blockIdx.x, h = bh & 15, b = bh >> 4;
    const int qb   = 31 - (int)blockIdx.y;
    const int iw   = qb * 64 + wv * 16;
    const int i_   = iw + l15;

    const ushort_t* Qh = Q  + (size_t)bh * 2048 * 64;
    const ushort_t* Kh = K  + (size_t)bh * 2048 * 64;
    const ushort_t* Vh = Vt + (size_t)bh * 64 * 2048;

    const float LOG2E = 1.44269504088896340736f;
    const float sl2 = exp2f(-0.5f * (float)(h + 1)) * LOG2E;
    const float c1  = 0.125f * LOG2E;

    // ALiBi reach cap: j-tiles with sl2*(tile start) > 46 only produce
    // exp2 underflow (relative contribution < 2^-27) -> skip them.
    const int jcap   = (int)(46.0f / (sl2 * 64.0f)) + 1;
    const int ntiles = min(qb + 1, jcap);
    const int iters  = (ntiles + 3) >> 2;        // block-uniform
    const int jBeg   = grp * iters;
    const int jEnd   = min(ntiles, jBeg + iters);

    ushort_t* Ksg = SM + grp * 9216;             // [j][d], stride 72
    ushort_t* Vsg = Ksg + 4608;                  // [d][j], stride 72

    bf16x8 qf0 = *(const bf16x8*)(Qh + (size_t)(iw + l15) * 64 + quad * 8);
    bf16x8 qf1 = *(const bf16x8*)(Qh + (size_t)(iw + l15) * 64 + 32 + quad * 8);

    s4 onesf;
    #pragma unroll
    for (int e = 0; e < 4; ++e) onesf[e] = (short)0x3F80;

    // per-lane bias base: -sl2*(quad*4+r); per-subtile only add -sl2*j0s.
    float nb[4];
    #pragma unroll
    for (int r = 0; r < 4; ++r) nb[r] = -sl2 * (float)(quad * 4 + r);

    f32x4 accv[4] = {};
    f32x4 accl = {};

    const int sr = ltid >> 2, sc = (ltid & 3) * 16;

    int j0 = min(jBeg, ntiles - 1) * 64;         // clamped (valid mem for idle grps)
    uint4 ka0 = *(const uint4*)(Kh + (size_t)(j0 + sr) * 64 + sc);
    uint4 ka1 = *(const uint4*)(Kh + (size_t)(j0 + sr) * 64 + sc + 8);
    uint4 va0 = *(const uint4*)(Vh + (size_t)sr * 2048 + j0 + sc);
    uint4 va1 = *(const uint4*)(Vh + (size_t)sr * 2048 + j0 + sc + 8);

    auto subtile = [&](int jt, int js, bool masked) {
        const int j0s = jt * 64 + js * 16;
        const float bj = -sl2 * (float)j0s;      // wave-uniform per subtile
        f32x4 sT = {};
        bf16x8 kf0 = *(const bf16x8*)(Ksg + (js * 16 + l15) * 72 + quad * 8);
        bf16x8 kf1 = *(const bf16x8*)(Ksg + (js * 16 + l15) * 72 + 32 + quad * 8);
        sT = MFMA_16x16x32(kf0, qf0, sT);
        sT = MFMA_16x16x32(kf1, qf1, sT);
        unsigned u[4];
        #pragma unroll
        for (int r = 0; r < 4; ++r) {
            float p = exp2f(fmaf(sT[r], c1, nb[r] + bj));
            if (masked && (j0s + quad * 4 + r) > i_) p = 0.0f;
            u[r] = __builtin_bit_cast(unsigned, p) + 0x8000u;
        }
        uint2 dd = { (u[0] >> 16) | (u[1] & 0xFFFF0000u),
                     (u[2] >> 16) | (u[3] & 0xFFFF0000u) };
        s4 pf = __builtin_bit_cast(s4, dd);
        accl = MFMA16(onesf, pf, accl);
        #pragma unroll
        for (int dt = 0; dt < 4; ++dt) {
            s4 vf = *(const s4*)(Vsg + (dt * 16 + l15) * 72 + js * 16 + quad * 4);
            accv[dt] = MFMA16(vf, pf, accv[dt]);
        }
    };

    for (int it = 0; it < iters; ++it) {
        const int jt = jBeg + it;
        __syncthreads();
        *(uint4*)(Ksg + sr * 72 + sc)     = ka0;
        *(uint4*)(Ksg + sr * 72 + sc + 8) = ka1;
        *(uint4*)(Vsg + sr * 72 + sc)     = va0;
        *(uint4*)(Vsg + sr * 72 + sc + 8) = va1;
        __syncthreads();
        if (it + 1 < iters) {
            int jn = min(jt + 1, ntiles - 1) * 64;
            ka0 = *(const uint4*)(Kh + (size_t)(jn + sr) * 64 + sc);
            ka1 = *(const uint4*)(Kh + (size_t)(jn + sr) * 64 + sc + 8);
            va0 = *(const uint4*)(Vh + (size_t)sr * 2048 + jn + sc);
            va1 = *(const uint4*)(Vh + (size_t)sr * 2048 + jn + sc + 8);
        }
        if (jt < jEnd) {                          // group-uniform guard
            if (jt < qb) {
                #pragma unroll
                for (int js = 0; js < 4; ++js) subtile(jt, js, false);
            } else {                              // diagonal tile jt == qb
                for (int js = 0; js < wv; ++js) subtile(jt, js, false);
                subtile(jt, wv, true);
            }
        }
    }

    // ---- merge 4 group partials through LDS (reuse K/V area) ----
    __syncthreads();
    float* M = (float*)SM;                        // 1024*17*4B = 68KB <= 72KB
    const int mb = tid * 17;
    #pragma unroll
    for (int dt = 0; dt < 4; ++dt)
        #pragma unroll
        for (int r = 0; r < 4; ++r) M[mb + dt * 4 + r] = accv[dt][r];
    M[mb + 16] = accl[0];
    __syncthreads();
    if (grp == 0) {
        float den = accl[0];
        #pragma unroll
        for (int g = 1; g < 4; ++g) {
            const int gb = (g * 256 + ltid) * 17;
            #pragma unroll
            for (int dt = 0; dt < 4; ++dt)
                #pragma unroll
                for (int r = 0; r < 4; ++r) accv[dt][r] += M[gb + dt * 4 + r];
            den += M[gb + 16];
        }
        const float inv = 1.0f / fmaxf(den, 1e-30f);
        const size_t obase = ((size_t)(b * 2048 + i_)) * 1024 + h * 64;
        #pragma unroll
        for (int dt = 0; dt < 4; ++dt) {
            ushort_t pk[4];
            #pragma unroll
            for (int r = 0; r < 4; ++r) pk[r] = f2bf(accv[dt][r] * inv);
            *(ushort2*)(AO + obase + dt * 16 + quad * 4)     = *(ushort2*)&pk[0];
            *(ushort2*)(AO + obase + dt * 16 + quad * 4 + 2) = *(ushort2*)&pk[2];
        }
    }
}

// ---------------- Output projection GEMM + bias, global_load_lds -> FP32 ----------------
__global__ __launch_bounds__(256) void oproj_gemm(
    const ushort_t* __restrict__ A, const ushort_t* __restrict__ WT,
    const ushort_t* __restrict__ bias, float* __restrict__ out)
{
    __shared__ ushort_t As[128 * 32];
    __shared__ ushort_t Bs[128 * 32];

    const int tid  = threadIdx.x;
    const int m0   = blockIdx.y * 128, n0 = blockIdx.x * 128;
    const int lane = tid & 63, wv = tid >> 6;
    const int quad = lane >> 4, l15 = lane & 15;
    const int wm = (wv & 1) * 64, wn = (wv >> 1) * 64;

    const int lrow = lane >> 2;
    const int schk = (lane & 3) ^ ((lane >> 3) & 3);
    const int ra0_ = wv * 16 + lrow;
    ushort_t* aB0 = As + wv * 512;
    ushort_t* aB1 = As + 2048 + wv * 512;
    ushort_t* bB0 = Bs + wv * 512;
    ushort_t* bB1 = Bs + 2048 + wv * 512;
    const int sp = quad ^ ((l15 >> 1) & 3);

    f32x4 acc[4][4] = {};

    for (int kt = 0; kt < 32; ++kt) {
        const int k0 = kt * 32;
        __syncthreads();
        gl_lds16(A  + (size_t)(m0 + ra0_)      * 1024 + k0 + schk * 8, aB0);
        gl_lds16(A  + (size_t)(m0 + 64 + ra0_) * 1024 + k0 + schk * 8, aB1);
        gl_lds16(WT + (size_t)(n0 + ra0_)      * 1024 + k0 + schk * 8, bB0);
        gl_lds16(WT + (size_t)(n0 + 64 + ra0_) * 1024 + k0 + schk * 8, bB1);
        __syncthreads();

        bf16x8 af[4], bfr[4];
        #pragma unroll
        for (int t = 0; t < 4; ++t) {
            af[t]  = *(const bf16x8*)(As + (wm + t * 16 + l15) * 32 + sp * 8);
            bfr[t] = *(const bf16x8*)(Bs + (wn + t * 16 + l15) * 32 + sp * 8);
        }
        #pragma unroll
        for (int mt = 0; mt < 4; ++mt)
            #pragma unroll
            for (int nt = 0; nt < 4; ++nt)
                acc[mt][nt] = MFMA_16x16x32(af[mt], bfr[nt], acc[mt][nt]);
    }

    #pragma unroll
    for (int mt = 0; mt < 4; ++mt) {
        #pragma unroll
        for (int nt = 0; nt < 4; ++nt) {
            #pragma unroll
            for (int r = 0; r < 4; ++r) {
                int m = m0 + wm + mt * 16 + quad * 4 + r;
                int c = n0 + wn + nt * 16 + l15;
                out[(size_t)m * 1024 + c] = acc[mt][nt][r] + bf2f(bias[c]);
            }
        }
    }
}

extern "C" void kernel_launch(void* const* d_in, const int* in_sizes, int n_in,
                              void* d_out, int out_size, void* d_ws, size_t ws_size,
                              hipStream_t stream) {
    const void* X  = d_in[0];
    const void* Wq = d_in[1];
    const void* Wk = d_in[2];
    const void* Wv = d_in[3];
    const void* Wo = d_in[4];
    const void* bo = d_in[5];

    const size_t M = 1024 * 1024;
    ushort_t* ws  = (ushort_t*)d_ws;
    ushort_t* Qb  = ws;
    ushort_t* Kb  = ws + 4 * M;
    ushort_t* Vt  = ws + 8 * M;
    ushort_t* Xc  = ws + 12 * M;    // shared with AO (Xc dead after qkv_gemm)
    ushort_t* AO  = ws + 12 * M;
    ushort_t* WqT = ws + 16 * M;
    ushort_t* WkT = ws + 17 * M;
    ushort_t* WvT = ws + 18 * M;
    ushort_t* WoT = ws + 19 * M;
    ushort_t* boc = ws + 20 * M;
    float* out = (float*)d_out;

    convert_x<<<2049, 256, 0, stream>>>(X, Wq, bo, Xc, boc);
    transpose_w<<<dim3(16, 16, 4), 256, 0, stream>>>(Wq, Wk, Wv, Wo, WqT, WkT, WvT, WoT);
    qkv_gemm<<<dim3(8, 32, 3), 256, 0, stream>>>(Xc, WqT, WkT, WvT, Qb, Kb, Vt);
    attn_kernel<<<dim3(32, 32), 1024, 0, stream>>>(Qb, Kb, Vt, AO);
    oproj_gemm<<<dim3(8, 32), 256, 0, stream>>>(AO, WoT, boc, out);
}

// Round 5
// 187.124 us; speedup vs baseline: 1.0811x; 1.0811x over previous
//
#include <hip/hip_runtime.h>
#include <hip/hip_bf16.h>

// B=2, N=2048, D=1024, H=16, DH=64. Output fp32; inputs runtime-detected and
// converted once. R12: (a) qkv/oproj staging via global_load_lds width=16
// (m97 ladder step) with XOR chunk swizzle (store c^((r>>1)&3)) replacing
// padding; (b) attn diagonal-tile specialization (branch-free main subtiles).
// R14: attn ALiBi reach cap (sl2*j>46 tiles skipped; 0.54x work).
// R15 (REVERTED): 4-group split-j in 1024-thr block — idle groups staged
// duplicate tiles (2x LDS traffic for capped heads) + 16-wave barriers.
// R16: load-balance fix. id->CU is stride-256 round-robin, so grid (x=bh)
// pinned HEAD per CU: post-cap work min(qb+1,jcap(h)) gave h>=12 CUs 80
// tiles vs mean 36 (80 x 0.62us/tile = 47.9us measured ✓). Compile-time
// serpentine schedule (descending-work counting sort, round r slot k <-
// rank r*256 + (r odd ? 255-k : k)) balances per-CU sums to ~36 tiles.
// Kernel body identical to R14; only (bh,qb) lookup changed.
// R17: identical resubmit of R16 (infra failure, no measurement).
//
// ws (bf16 elems): Q@0(4M), K@4M, Vt@8M, Xc/AO@12M (shared), WqT@16M..WoT@19M,
// boc@20M. ~40MB.

typedef __bf16 bf16x8 __attribute__((ext_vector_type(8)));
typedef float f32x4 __attribute__((ext_vector_type(4)));
typedef short s4 __attribute__((ext_vector_type(4)));      // k16 MFMA A/B frag
typedef unsigned short ushort_t;

#define MFMA_16x16x32(a, b, c) __builtin_amdgcn_mfma_f32_16x16x32_bf16(a, b, c, 0, 0, 0)
#define MFMA16(a, b, c) __builtin_amdgcn_mfma_f32_16x16x16bf16_1k(a, b, c, 0, 0, 0)

__device__ __forceinline__ ushort_t f2bf(float f) {
    __hip_bfloat16 h = __float2bfloat16(f);
    return __builtin_bit_cast(ushort_t, h);
}
__device__ __forceinline__ float bf2f(ushort_t u) {
    unsigned x = ((unsigned)u) << 16;
    return __builtin_bit_cast(float, x);
}

// async global->LDS, 16B/lane; LDS dest = wave-uniform base + lane*16.
__device__ __forceinline__ void gl_lds16(const ushort_t* g, ushort_t* l) {
    __builtin_amdgcn_global_load_lds(
        (const __attribute__((address_space(1))) void*)g,
        (__attribute__((address_space(3))) void*)l, 16, 0, 0);
}

__device__ __forceinline__ unsigned detect_fp32(const void* wp) {
    const ushort_t* w = (const ushort_t*)wp;
    unsigned c = 0;
    #pragma unroll
    for (int i = 0; i < 128; ++i) c += (((w[i] >> 7) & 0xFF) >= 0x7F) ? 1u : 0u;
    return (c > 8) ? 1u : 0u;
}

__device__ __forceinline__ uint4 load8(const void* p, size_t idx, unsigned flag) {
    if (flag) {
        const float* f = (const float*)p + idx;
        float4 a = *(const float4*)f;
        float4 b = *(const float4*)(f + 4);
        ushort_t u[8] = { f2bf(a.x), f2bf(a.y), f2bf(a.z), f2bf(a.w),
                          f2bf(b.x), f2bf(b.y), f2bf(b.z), f2bf(b.w) };
        return *(uint4*)u;
    }
    return *(const uint4*)((const ushort_t*)p + idx);
}

// ---- R16 compile-time balanced schedule for attn: slot -> (qb<<5)|bh ----
// Work model: w(bh,qb) = min(qb+1, jcap[h]); jcap matches the kernel's
// runtime float formula (ordering is perf-only, correctness-independent).
struct Sched { unsigned short v[1024]; };
constexpr Sched make_sched() {
    Sched s{};
    int jc[16] = {1, 1, 2, 2, 3, 4, 6, 8, 12, 16, 23, 32, 32, 32, 32, 32};
    int sorted[1024] = {};
    int n = 0;
    for (int w = 32; w >= 1; --w) {                 // counting sort, descending
        for (int id = 0; id < 1024; ++id) {
            int bh = id & 31, qb = id >> 5;
            int cap = jc[bh & 15];
            int wi = (qb + 1 < cap) ? (qb + 1) : cap;
            if (wi == w) sorted[n++] = id;
        }
    }
    for (int r = 0; r < 4; ++r)                     // serpentine over rounds
        for (int k = 0; k < 256; ++k)
            s.v[r * 256 + k] = (unsigned short)sorted[r * 256 + ((r & 1) ? (255 - k) : k)];
    return s;
}
__constant__ Sched g_sched = make_sched();

// ---------------- convert X + bias ----------------
__global__ __launch_bounds__(256) void convert_x(
    const void* __restrict__ X, const void* __restrict__ Wq, const void* __restrict__ bo,
    ushort_t* __restrict__ Xc, ushort_t* __restrict__ boc)
{
    const unsigned flag = detect_fp32(Wq);
    const int blk = blockIdx.x;
    if (blk < 2048) {
        size_t idx = (size_t)blk * 2048 + (size_t)threadIdx.x * 8;
        *(uint4*)(Xc + idx) = load8(X, idx, flag);
    } else {
        size_t idx = (size_t)threadIdx.x * 8;
        if (idx < 1024) *(uint4*)(boc + idx) = load8(bo, idx, flag);
    }
}

// ---------------- transpose weights -> WT[n][k] ----------------
__global__ __launch_bounds__(256) void transpose_w(
    const void* __restrict__ Wq, const void* __restrict__ Wk,
    const void* __restrict__ Wv, const void* __restrict__ Wo,
    ushort_t* __restrict__ WqT, ushort_t* __restrict__ WkT,
    ushort_t* __restrict__ WvT, ushort_t* __restrict__ WoT)
{
    __shared__ ushort_t T[64][72];
    const unsigned flag = detect_fp32(Wq);
    const int z = blockIdx.z;
    const void* W = (z == 0) ? Wq : ((z == 1) ? Wk : ((z == 2) ? Wv : Wo));
    ushort_t* WT = (z == 0) ? WqT : ((z == 1) ? WkT : ((z == 2) ? WvT : WoT));

    const int k0 = blockIdx.y * 64, n0 = blockIdx.x * 64;
    const int r = threadIdx.x >> 2, c = (threadIdx.x & 3) * 16;

    *(uint4*)&T[r][c]     = load8(W, (size_t)(k0 + r) * 1024 + n0 + c,     flag);
    *(uint4*)&T[r][c + 8] = load8(W, (size_t)(k0 + r) * 1024 + n0 + c + 8, flag);
    __syncthreads();
    ushort_t tmp[16];
    #pragma unroll
    for (int j = 0; j < 16; ++j) tmp[j] = T[c + j][r];
    *(uint4*)(WT + (size_t)(n0 + r) * 1024 + k0 + c)     = *(uint4*)&tmp[0];
    *(uint4*)(WT + (size_t)(n0 + r) * 1024 + k0 + c + 8) = *(uint4*)&tmp[8];
}

// ---------------- QKV projection GEMM, 128x128, global_load_lds staging ----------------
// grid (8, 32, 3), block 256 (4 waves), BK=32. Unpadded LDS 128x32 shorts.
// Swizzle: LDS (row r, chunk c) holds global k-chunk c^((r>>1)&3).
// Store side: lane l writes chunk l&3 of row (t*64+wv*16+(l>>2)) -> source
// chunk (l&3)^((l>>3)&3). Read side: row R=wm+t*16+l15 chunk q at position
// q^((l15>>1)&3). Conflict-free (8 dwords/bank = b128 minimum).
__global__ __launch_bounds__(256) void qkv_gemm(
    const ushort_t* __restrict__ X, const ushort_t* __restrict__ WqT,
    const ushort_t* __restrict__ WkT, const ushort_t* __restrict__ WvT,
    ushort_t* __restrict__ Q, ushort_t* __restrict__ K, ushort_t* __restrict__ Vt)
{
    __shared__ ushort_t As[128 * 32];
    __shared__ ushort_t Bs[128 * 32];

    const int z = blockIdx.z;
    const ushort_t* WT = (z == 0) ? WqT : ((z == 1) ? WkT : WvT);

    const int tid  = threadIdx.x;
    const int m0   = blockIdx.y * 128, n0 = blockIdx.x * 128;
    const int lane = tid & 63, wv = tid >> 6;
    const int quad = lane >> 4, l15 = lane & 15;
    const int wm = (wv & 1) * 64, wn = (wv >> 1) * 64;

    const int lrow = lane >> 2;                         // 0..15
    const int schk = (lane & 3) ^ ((lane >> 3) & 3);    // swizzled source chunk
    const int ra0_ = wv * 16 + lrow;                    // issue-0 row
    ushort_t* aB0 = As + wv * 512;                      // wave-uniform LDS bases
    ushort_t* aB1 = As + 2048 + wv * 512;
    ushort_t* bB0 = Bs + wv * 512;
    ushort_t* bB1 = Bs + 2048 + wv * 512;
    const int sp = quad ^ ((l15 >> 1) & 3);             // read chunk position

    f32x4 acc[4][4] = {};

    for (int kt = 0; kt < 32; ++kt) {
        const int k0 = kt * 32;
        __syncthreads();
        gl_lds16(X  + (size_t)(m0 + ra0_)      * 1024 + k0 + schk * 8, aB0);
        gl_lds16(X  + (size_t)(m0 + 64 + ra0_) * 1024 + k0 + schk * 8, aB1);
        gl_lds16(WT + (size_t)(n0 + ra0_)      * 1024 + k0 + schk * 8, bB0);
        gl_lds16(WT + (size_t)(n0 + 64 + ra0_) * 1024 + k0 + schk * 8, bB1);
        __syncthreads();   // compiler emits vmcnt(0) drain -> LDS data visible

        bf16x8 af[4], bfr[4];
        #pragma unroll
        for (int t = 0; t < 4; ++t) {
            af[t]  = *(const bf16x8*)(As + (wm + t * 16 + l15) * 32 + sp * 8);
            bfr[t] = *(const bf16x8*)(Bs + (wn + t * 16 + l15) * 32 + sp * 8);
        }
        #pragma unroll
        for (int mt = 0; mt < 4; ++mt)
            #pragma unroll
            for (int nt = 0; nt < 4; ++nt)
                acc[mt][nt] = MFMA_16x16x32(af[mt], bfr[nt], acc[mt][nt]);
    }

    #pragma unroll
    for (int mt = 0; mt < 4; ++mt) {
        #pragma unroll
        for (int nt = 0; nt < 4; ++nt) {
            if (z == 2) {
                int c  = n0 + wn + nt * 16 + l15;
                int h  = c >> 6, dh = c & 63;
                int mA = m0 + wm + mt * 16 + quad * 4;
                int b  = mA >> 11, nseq = mA & 2047;
                ushort_t pk[4];
                #pragma unroll
                for (int r = 0; r < 4; ++r) pk[r] = f2bf(acc[mt][nt][r]);
                *(ushort2*)(Vt + ((size_t)((b * 16 + h) * 64 + dh)) * 2048 + nseq)     = *(ushort2*)&pk[0];
                *(ushort2*)(Vt + ((size_t)((b * 16 + h) * 64 + dh)) * 2048 + nseq + 2) = *(ushort2*)&pk[2];
            } else {
                ushort_t* dst = (z == 0) ? Q : K;
                #pragma unroll
                for (int r = 0; r < 4; ++r) {
                    int m = m0 + wm + mt * 16 + quad * 4 + r;
                    int c = n0 + wn + nt * 16 + l15;
                    int b = m >> 11, nseq = m & 2047;
                    int h = c >> 6, dh = c & 63;
                    dst[((size_t)((b * 16 + h) * 2048 + nseq)) * 64 + dh] = f2bf(acc[mt][nt][r]);
                }
            }
        }
    }
}

// ---------------- MFMA flash attention: LDS-shared K/V + k16 identity ----------------
// grid 1024 flat, block 256 = 4 waves; (bh,qb) from g_sched (serpentine LPT).
// Main tiles: branch-free subtiles; diagonal tile specialized (mask only there).
// Softmax relative to j=0 (row factor exp2(sl2*i) cancels); tiles with
// sl2*j0 > 46 contribute < 2^-27 of softmax -> skipped (R14 cap).
__global__ __launch_bounds__(256) void attn_kernel(
    const ushort_t* __restrict__ Q, const ushort_t* __restrict__ K,
    const ushort_t* __restrict__ Vt, ushort_t* __restrict__ AO)
{
    __shared__ ushort_t Ks[64 * 72];   // [j][d], stride 72
    __shared__ ushort_t Vs[64 * 72];   // [d][j], stride 72

    const int tid  = threadIdx.x;
    const int wv   = tid >> 6, lane = tid & 63;
    const int quad = lane >> 4, l15 = lane & 15;
    const int item = g_sched.v[blockIdx.x];
    const int bh   = item & 31, h = bh & 15, b = bh >> 4;
    const int qb   = item >> 5;
    const int iw   = qb * 64 + wv * 16;
    const int i_   = iw + l15;

    const ushort_t* Qh = Q  + (size_t)bh * 2048 * 64;
    const ushort_t* Kh = K  + (size_t)bh * 2048 * 64;
    const ushort_t* Vh = Vt + (size_t)bh * 64 * 2048;

    const float LOG2E = 1.44269504088896340736f;
    const float sl2 = exp2f(-0.5f * (float)(h + 1)) * LOG2E;
    const float c1  = 0.125f * LOG2E;

    // ALiBi reach cap: j-tiles with sl2*(tile start) > 46 only produce
    // exp2 underflow (relative contribution < 2^-27) -> skip them.
    const int jcap   = (int)(46.0f / (sl2 * 64.0f)) + 1;
    const int ntiles = min(qb + 1, jcap);

    bf16x8 qf0 = *(const bf16x8*)(Qh + (size_t)(iw + l15) * 64 + quad * 8);
    bf16x8 qf1 = *(const bf16x8*)(Qh + (size_t)(iw + l15) * 64 + 32 + quad * 8);

    s4 onesf;
    #pragma unroll
    for (int e = 0; e < 4; ++e) onesf[e] = (short)0x3F80;

    // per-lane bias base: -sl2*(quad*4+r); per-subtile only add -sl2*j0s.
    float nb[4];
    #pragma unroll
    for (int r = 0; r < 4; ++r) nb[r] = -sl2 * (float)(quad * 4 + r);

    f32x4 accv[4] = {};
    f32x4 accl = {};

    const int sr = tid >> 2, sc = (tid & 3) * 16;

    uint4 ka0 = *(const uint4*)(Kh + (size_t)sr * 64 + sc);
    uint4 ka1 = *(const uint4*)(Kh + (size_t)sr * 64 + sc + 8);
    uint4 va0 = *(const uint4*)(Vh + (size_t)sr * 2048 + sc);
    uint4 va1 = *(const uint4*)(Vh + (size_t)sr * 2048 + sc + 8);

    auto subtile = [&](int jt, int js, bool masked) {
        const int j0s = jt * 64 + js * 16;
        const float bj = -sl2 * (float)j0s;   // wave-uniform per subtile
        f32x4 sT = {};
        bf16x8 kf0 = *(const bf16x8*)(Ks + (js * 16 + l15) * 72 + quad * 8);
        bf16x8 kf1 = *(const bf16x8*)(Ks + (js * 16 + l15) * 72 + 32 + quad * 8);
        sT = MFMA_16x16x32(kf0, qf0, sT);
        sT = MFMA_16x16x32(kf1, qf1, sT);
        unsigned u[4];
        #pragma unroll
        for (int r = 0; r < 4; ++r) {
            float p = exp2f(fmaf(sT[r], c1, nb[r] + bj));
            if (masked && (j0s + quad * 4 + r) > i_) p = 0.0f;
            u[r] = __builtin_bit_cast(unsigned, p) + 0x8000u;
        }
        uint2 dd = { (u[0] >> 16) | (u[1] & 0xFFFF0000u),
                     (u[2] >> 16) | (u[3] & 0xFFFF0000u) };
        s4 pf = __builtin_bit_cast(s4, dd);
        accl = MFMA16(onesf, pf, accl);
        #pragma unroll
        for (int dt = 0; dt < 4; ++dt) {
            s4 vf = *(const s4*)(Vs + (dt * 16 + l15) * 72 + js * 16 + quad * 4);
            accv[dt] = MFMA16(vf, pf, accv[dt]);
        }
    };

    for (int jt = 0; jt < ntiles; ++jt) {
        __syncthreads();
        *(uint4*)(Ks + sr * 72 + sc)     = ka0;
        *(uint4*)(Ks + sr * 72 + sc + 8) = ka1;
        *(uint4*)(Vs + sr * 72 + sc)     = va0;
        *(uint4*)(Vs + sr * 72 + sc + 8) = va1;
        __syncthreads();
        if (jt + 1 < ntiles) {
            int j0n = (jt + 1) * 64;
            ka0 = *(const uint4*)(Kh + (size_t)(j0n + sr) * 64 + sc);
            ka1 = *(const uint4*)(Kh + (size_t)(j0n + sr) * 64 + sc + 8);
            va0 = *(const uint4*)(Vh + (size_t)sr * 2048 + j0n + sc);
            va1 = *(const uint4*)(Vh + (size_t)sr * 2048 + j0n + sc + 8);
        }
        if (jt < qb) {
            #pragma unroll
            for (int js = 0; js < 4; ++js) subtile(jt, js, false);
        } else {
            for (int js = 0; js < wv; ++js) subtile(jt, js, false);
            subtile(jt, wv, true);
        }
    }

    const float inv = 1.0f / fmaxf(accl[0], 1e-30f);
    const size_t obase = ((size_t)(b * 2048 + i_)) * 1024 + h * 64;
    #pragma unroll
    for (int dt = 0; dt < 4; ++dt) {
        ushort_t pk[4];
        #pragma unroll
        for (int r = 0; r < 4; ++r) pk[r] = f2bf(accv[dt][r] * inv);
        *(ushort2*)(AO + obase + dt * 16 + quad * 4)     = *(ushort2*)&pk[0];
        *(ushort2*)(AO + obase + dt * 16 + quad * 4 + 2) = *(ushort2*)&pk[2];
    }
}

// ---------------- Output projection GEMM + bias, global_load_lds -> FP32 ----------------
__global__ __launch_bounds__(256) void oproj_gemm(
    const ushort_t* __restrict__ A, const ushort_t* __restrict__ WT,
    const ushort_t* __restrict__ bias, float* __restrict__ out)
{
    __shared__ ushort_t As[128 * 32];
    __shared__ ushort_t Bs[128 * 32];

    const int tid  = threadIdx.x;
    const int m0   = blockIdx.y * 128, n0 = blockIdx.x * 128;
    const int lane = tid & 63, wv = tid >> 6;
    const int quad = lane >> 4, l15 = lane & 15;
    const int wm = (wv & 1) * 64, wn = (wv >> 1) * 64;

    const int lrow = lane >> 2;
    const int schk = (lane & 3) ^ ((lane >> 3) & 3);
    const int ra0_ = wv * 16 + lrow;
    ushort_t* aB0 = As + wv * 512;
    ushort_t* aB1 = As + 2048 + wv * 512;
    ushort_t* bB0 = Bs + wv * 512;
    ushort_t* bB1 = Bs + 2048 + wv * 512;
    const int sp = quad ^ ((l15 >> 1) & 3);

    f32x4 acc[4][4] = {};

    for (int kt = 0; kt < 32; ++kt) {
        const int k0 = kt * 32;
        __syncthreads();
        gl_lds16(A  + (size_t)(m0 + ra0_)      * 1024 + k0 + schk * 8, aB0);
        gl_lds16(A  + (size_t)(m0 + 64 + ra0_) * 1024 + k0 + schk * 8, aB1);
        gl_lds16(WT + (size_t)(n0 + ra0_)      * 1024 + k0 + schk * 8, bB0);
        gl_lds16(WT + (size_t)(n0 + 64 + ra0_) * 1024 + k0 + schk * 8, bB1);
        __syncthreads();

        bf16x8 af[4], bfr[4];
        #pragma unroll
        for (int t = 0; t < 4; ++t) {
            af[t]  = *(const bf16x8*)(As + (wm + t * 16 + l15) * 32 + sp * 8);
            bfr[t] = *(const bf16x8*)(Bs + (wn + t * 16 + l15) * 32 + sp * 8);
        }
        #pragma unroll
        for (int mt = 0; mt < 4; ++mt)
            #pragma unroll
            for (int nt = 0; nt < 4; ++nt)
                acc[mt][nt] = MFMA_16x16x32(af[mt], bfr[nt], acc[mt][nt]);
    }

    #pragma unroll
    for (int mt = 0; mt < 4; ++mt) {
        #pragma unroll
        for (int nt = 0; nt < 4; ++nt) {
            #pragma unroll
            for (int r = 0; r < 4; ++r) {
                int m = m0 + wm + mt * 16 + quad * 4 + r;
                int c = n0 + wn + nt * 16 + l15;
                out[(size_t)m * 1024 + c] = acc[mt][nt][r] + bf2f(bias[c]);
            }
        }
    }
}

extern "C" void kernel_launch(void* const* d_in, const int* in_sizes, int n_in,
                              void* d_out, int out_size, void* d_ws, size_t ws_size,
                              hipStream_t stream) {
    const void* X  = d_in[0];
    const void* Wq = d_in[1];
    const void* Wk = d_in[2];
    const void* Wv = d_in[3];
    const void* Wo = d_in[4];
    const void* bo = d_in[5];

    const size_t M = 1024 * 1024;
    ushort_t* ws  = (ushort_t*)d_ws;
    ushort_t* Qb  = ws;
    ushort_t* Kb  = ws + 4 * M;
    ushort_t* Vt  = ws + 8 * M;
    ushort_t* Xc  = ws + 12 * M;    // shared with AO (Xc dead after qkv_gemm)
    ushort_t* AO  = ws + 12 * M;
    ushort_t* WqT = ws + 16 * M;
    ushort_t* WkT = ws + 17 * M;
    ushort_t* WvT = ws + 18 * M;
    ushort_t* WoT = ws + 19 * M;
    ushort_t* boc = ws + 20 * M;
    float* out = (float*)d_out;

    convert_x<<<2049, 256, 0, stream>>>(X, Wq, bo, Xc, boc);
    transpose_w<<<dim3(16, 16, 4), 256, 0, stream>>>(Wq, Wk, Wv, Wo, WqT, WkT, WvT, WoT);
    qkv_gemm<<<dim3(8, 32, 3), 256, 0, stream>>>(Xc, WqT, WkT, WvT, Qb, Kb, Vt);
    attn_kernel<<<1024, 256, 0, stream>>>(Qb, Kb, Vt, AO);
    oproj_gemm<<<dim3(8, 32), 256, 0, stream>>>(AO, WoT, boc, out);
}

// Round 6
// 186.542 us; speedup vs baseline: 1.0845x; 1.0031x over previous
//
#include <hip/hip_runtime.h>
#include <hip/hip_bf16.h>

// B=2, N=2048, D=1024, H=16, DH=64. Output fp32; inputs runtime-detected and
// converted once. R12: (a) qkv/oproj staging via global_load_lds width=16
// (m97 ladder step) with XOR chunk swizzle (store c^((r>>1)&3)) replacing
// padding; (b) attn diagonal-tile specialization (branch-free main subtiles).
// R14: attn ALiBi reach cap (sl2*j>46 tiles skipped; 0.54x work).
// R15 (REVERTED): 4-group split-j — duplicate staging + 16-wave barriers.
// R16: global serpentine LPT schedule: 47.9 -> ~41us. Post-mortem: balance
// worked but global mixing scattered ~16 heads per XCD (>8MB K/V >> 4MB L2,
// vs R14's pinned 4 heads = 2MB) -> per-tile cost rose ~0.6 -> ~1.1us.
// R18: XCD-grouped LPT. 8 groups x 4 bh with near-equal work sums
// (1151x4, 1226x2, 1115x2 tile-units; W(h)=sum_qb min(qb+1,jcap)) assigned
// to XCD = slot mod 8; within each XCD the 128 items are desc-sorted and
// serpentined over 32 CUs x 4 rounds. Keeps R14's 2MB/XCD locality AND
// balances per-CU sums to ~38-40 tiles. Kernel body identical to R14.
//
// ws (bf16 elems): Q@0(4M), K@4M, Vt@8M, Xc/AO@12M (shared), WqT@16M..WoT@19M,
// boc@20M. ~40MB.

typedef __bf16 bf16x8 __attribute__((ext_vector_type(8)));
typedef float f32x4 __attribute__((ext_vector_type(4)));
typedef short s4 __attribute__((ext_vector_type(4)));      // k16 MFMA A/B frag
typedef unsigned short ushort_t;

#define MFMA_16x16x32(a, b, c) __builtin_amdgcn_mfma_f32_16x16x32_bf16(a, b, c, 0, 0, 0)
#define MFMA16(a, b, c) __builtin_amdgcn_mfma_f32_16x16x16bf16_1k(a, b, c, 0, 0, 0)

__device__ __forceinline__ ushort_t f2bf(float f) {
    __hip_bfloat16 h = __float2bfloat16(f);
    return __builtin_bit_cast(ushort_t, h);
}
__device__ __forceinline__ float bf2f(ushort_t u) {
    unsigned x = ((unsigned)u) << 16;
    return __builtin_bit_cast(float, x);
}

// async global->LDS, 16B/lane; LDS dest = wave-uniform base + lane*16.
__device__ __forceinline__ void gl_lds16(const ushort_t* g, ushort_t* l) {
    __builtin_amdgcn_global_load_lds(
        (const __attribute__((address_space(1))) void*)g,
        (__attribute__((address_space(3))) void*)l, 16, 0, 0);
}

__device__ __forceinline__ unsigned detect_fp32(const void* wp) {
    const ushort_t* w = (const ushort_t*)wp;
    unsigned c = 0;
    #pragma unroll
    for (int i = 0; i < 128; ++i) c += (((w[i] >> 7) & 0xFF) >= 0x7F) ? 1u : 0u;
    return (c > 8) ? 1u : 0u;
}

__device__ __forceinline__ uint4 load8(const void* p, size_t idx, unsigned flag) {
    if (flag) {
        const float* f = (const float*)p + idx;
        float4 a = *(const float4*)f;
        float4 b = *(const float4*)(f + 4);
        ushort_t u[8] = { f2bf(a.x), f2bf(a.y), f2bf(a.z), f2bf(a.w),
                          f2bf(b.x), f2bf(b.y), f2bf(b.z), f2bf(b.w) };
        return *(uint4*)u;
    }
    return *(const uint4*)((const ushort_t*)p + idx);
}

// ---- R18 XCD-grouped LPT schedule for attn: slot -> (qb<<5)|bh ----
// XCD = slot mod 8 (HW round-robin); each XCD owns 4 bh (2MB K/V, L2-fit).
// Within an XCD: 128 items desc-sorted by w=min(qb+1,jcap), serpentine over
// 32 CUs x 4 rounds. Ordering is perf-only, correctness-independent.
struct Sched { unsigned short v[1024]; };
constexpr Sched make_sched() {
    Sched s{};
    int jc[16] = {1, 1, 2, 2, 3, 4, 6, 8, 12, 16, 23, 32, 32, 32, 32, 32};
    // groups of 4 bh with near-equal work sums (1151,1151,1151,1151,1226,1226,1115,1115)
    int grp[8][4] = {
        {11,      12,      0,       2},        // b0: 528+528+32+63
        {13,      14,      1,       3},        // b0
        {16 + 11, 16 + 12, 16 + 0,  16 + 2},   // b1
        {16 + 13, 16 + 14, 16 + 1,  16 + 3},   // b1
        {15,      10,      5,       4},        // b0: 528+483+122+93
        {16 + 15, 16 + 10, 16 + 5,  16 + 4},   // b1
        {9,       8,       7,       6},        // b0: 392+318+228+177
        {16 + 9,  16 + 8,  16 + 7,  16 + 6},   // b1
    };
    for (int x = 0; x < 8; ++x) {
        int items[128] = {};
        int n = 0;
        for (int w = 32; w >= 1; --w)                   // counting sort, desc
            for (int gi = 0; gi < 4; ++gi) {
                int bh = grp[x][gi], h = bh & 15;
                for (int qb = 0; qb < 32; ++qb) {
                    int wi = (qb + 1 < jc[h]) ? (qb + 1) : jc[h];
                    if (wi == w) items[n++] = (qb << 5) | bh;
                }
            }
        for (int t = 0; t < 128; ++t) {
            int r = t >> 5, p = t & 31;
            int cu = (r & 1) ? (31 - p) : p;            // serpentine
            s.v[r * 256 + cu * 8 + x] = (unsigned short)items[t];
        }
    }
    return s;
}
__constant__ Sched g_sched = make_sched();

// ---------------- convert X + bias ----------------
__global__ __launch_bounds__(256) void convert_x(
    const void* __restrict__ X, const void* __restrict__ Wq, const void* __restrict__ bo,
    ushort_t* __restrict__ Xc, ushort_t* __restrict__ boc)
{
    const unsigned flag = detect_fp32(Wq);
    const int blk = blockIdx.x;
    if (blk < 2048) {
        size_t idx = (size_t)blk * 2048 + (size_t)threadIdx.x * 8;
        *(uint4*)(Xc + idx) = load8(X, idx, flag);
    } else {
        size_t idx = (size_t)threadIdx.x * 8;
        if (idx < 1024) *(uint4*)(boc + idx) = load8(bo, idx, flag);
    }
}

// ---------------- transpose weights -> WT[n][k] ----------------
__global__ __launch_bounds__(256) void transpose_w(
    const void* __restrict__ Wq, const void* __restrict__ Wk,
    const void* __restrict__ Wv, const void* __restrict__ Wo,
    ushort_t* __restrict__ WqT, ushort_t* __restrict__ WkT,
    ushort_t* __restrict__ WvT, ushort_t* __restrict__ WoT)
{
    __shared__ ushort_t T[64][72];
    const unsigned flag = detect_fp32(Wq);
    const int z = blockIdx.z;
    const void* W = (z == 0) ? Wq : ((z == 1) ? Wk : ((z == 2) ? Wv : Wo));
    ushort_t* WT = (z == 0) ? WqT : ((z == 1) ? WkT : ((z == 2) ? WvT : WoT));

    const int k0 = blockIdx.y * 64, n0 = blockIdx.x * 64;
    const int r = threadIdx.x >> 2, c = (threadIdx.x & 3) * 16;

    *(uint4*)&T[r][c]     = load8(W, (size_t)(k0 + r) * 1024 + n0 + c,     flag);
    *(uint4*)&T[r][c + 8] = load8(W, (size_t)(k0 + r) * 1024 + n0 + c + 8, flag);
    __syncthreads();
    ushort_t tmp[16];
    #pragma unroll
    for (int j = 0; j < 16; ++j) tmp[j] = T[c + j][r];
    *(uint4*)(WT + (size_t)(n0 + r) * 1024 + k0 + c)     = *(uint4*)&tmp[0];
    *(uint4*)(WT + (size_t)(n0 + r) * 1024 + k0 + c + 8) = *(uint4*)&tmp[8];
}

// ---------------- QKV projection GEMM, 128x128, global_load_lds staging ----------------
// grid (8, 32, 3), block 256 (4 waves), BK=32. Unpadded LDS 128x32 shorts.
// Swizzle: LDS (row r, chunk c) holds global k-chunk c^((r>>1)&3).
// Store side: lane l writes chunk l&3 of row (t*64+wv*16+(l>>2)) -> source
// chunk (l&3)^((l>>3)&3). Read side: row R=wm+t*16+l15 chunk q at position
// q^((l15>>1)&3). Conflict-free (8 dwords/bank = b128 minimum).
__global__ __launch_bounds__(256) void qkv_gemm(
    const ushort_t* __restrict__ X, const ushort_t* __restrict__ WqT,
    const ushort_t* __restrict__ WkT, const ushort_t* __restrict__ WvT,
    ushort_t* __restrict__ Q, ushort_t* __restrict__ K, ushort_t* __restrict__ Vt)
{
    __shared__ ushort_t As[128 * 32];
    __shared__ ushort_t Bs[128 * 32];

    const int z = blockIdx.z;
    const ushort_t* WT = (z == 0) ? WqT : ((z == 1) ? WkT : WvT);

    const int tid  = threadIdx.x;
    const int m0   = blockIdx.y * 128, n0 = blockIdx.x * 128;
    const int lane = tid & 63, wv = tid >> 6;
    const int quad = lane >> 4, l15 = lane & 15;
    const int wm = (wv & 1) * 64, wn = (wv >> 1) * 64;

    const int lrow = lane >> 2;                         // 0..15
    const int schk = (lane & 3) ^ ((lane >> 3) & 3);    // swizzled source chunk
    const int ra0_ = wv * 16 + lrow;                    // issue-0 row
    ushort_t* aB0 = As + wv * 512;                      // wave-uniform LDS bases
    ushort_t* aB1 = As + 2048 + wv * 512;
    ushort_t* bB0 = Bs + wv * 512;
    ushort_t* bB1 = Bs + 2048 + wv * 512;
    const int sp = quad ^ ((l15 >> 1) & 3);             // read chunk position

    f32x4 acc[4][4] = {};

    for (int kt = 0; kt < 32; ++kt) {
        const int k0 = kt * 32;
        __syncthreads();
        gl_lds16(X  + (size_t)(m0 + ra0_)      * 1024 + k0 + schk * 8, aB0);
        gl_lds16(X  + (size_t)(m0 + 64 + ra0_) * 1024 + k0 + schk * 8, aB1);
        gl_lds16(WT + (size_t)(n0 + ra0_)      * 1024 + k0 + schk * 8, bB0);
        gl_lds16(WT + (size_t)(n0 + 64 + ra0_) * 1024 + k0 + schk * 8, bB1);
        __syncthreads();   // compiler emits vmcnt(0) drain -> LDS data visible

        bf16x8 af[4], bfr[4];
        #pragma unroll
        for (int t = 0; t < 4; ++t) {
            af[t]  = *(const bf16x8*)(As + (wm + t * 16 + l15) * 32 + sp * 8);
            bfr[t] = *(const bf16x8*)(Bs + (wn + t * 16 + l15) * 32 + sp * 8);
        }
        #pragma unroll
        for (int mt = 0; mt < 4; ++mt)
            #pragma unroll
            for (int nt = 0; nt < 4; ++nt)
                acc[mt][nt] = MFMA_16x16x32(af[mt], bfr[nt], acc[mt][nt]);
    }

    #pragma unroll
    for (int mt = 0; mt < 4; ++mt) {
        #pragma unroll
        for (int nt = 0; nt < 4; ++nt) {
            if (z == 2) {
                int c  = n0 + wn + nt * 16 + l15;
                int h  = c >> 6, dh = c & 63;
                int mA = m0 + wm + mt * 16 + quad * 4;
                int b  = mA >> 11, nseq = mA & 2047;
                ushort_t pk[4];
                #pragma unroll
                for (int r = 0; r < 4; ++r) pk[r] = f2bf(acc[mt][nt][r]);
                *(ushort2*)(Vt + ((size_t)((b * 16 + h) * 64 + dh)) * 2048 + nseq)     = *(ushort2*)&pk[0];
                *(ushort2*)(Vt + ((size_t)((b * 16 + h) * 64 + dh)) * 2048 + nseq + 2) = *(ushort2*)&pk[2];
            } else {
                ushort_t* dst = (z == 0) ? Q : K;
                #pragma unroll
                for (int r = 0; r < 4; ++r) {
                    int m = m0 + wm + mt * 16 + quad * 4 + r;
                    int c = n0 + wn + nt * 16 + l15;
                    int b = m >> 11, nseq = m & 2047;
                    int h = c >> 6, dh = c & 63;
                    dst[((size_t)((b * 16 + h) * 2048 + nseq)) * 64 + dh] = f2bf(acc[mt][nt][r]);
                }
            }
        }
    }
}

// ---------------- MFMA flash attention: LDS-shared K/V + k16 identity ----------------
// grid 1024 flat, block 256 = 4 waves; (bh,qb) from g_sched (XCD-grouped LPT).
// Main tiles: branch-free subtiles; diagonal tile specialized (mask only there).
// Softmax relative to j=0 (row factor exp2(sl2*i) cancels); tiles with
// sl2*j0 > 46 contribute < 2^-27 of softmax -> skipped (R14 cap).
__global__ __launch_bounds__(256) void attn_kernel(
    const ushort_t* __restrict__ Q, const ushort_t* __restrict__ K,
    const ushort_t* __restrict__ Vt, ushort_t* __restrict__ AO)
{
    __shared__ ushort_t Ks[64 * 72];   // [j][d], stride 72
    __shared__ ushort_t Vs[64 * 72];   // [d][j], stride 72

    const int tid  = threadIdx.x;
    const int wv   = tid >> 6, lane = tid & 63;
    const int quad = lane >> 4, l15 = lane & 15;
    const int item = g_sched.v[blockIdx.x];
    const int bh   = item & 31, h = bh & 15, b = bh >> 4;
    const int qb   = item >> 5;
    const int iw   = qb * 64 + wv * 16;
    const int i_   = iw + l15;

    const ushort_t* Qh = Q  + (size_t)bh * 2048 * 64;
    const ushort_t* Kh = K  + (size_t)bh * 2048 * 64;
    const ushort_t* Vh = Vt + (size_t)bh * 64 * 2048;

    const float LOG2E = 1.44269504088896340736f;
    const float sl2 = exp2f(-0.5f * (float)(h + 1)) * LOG2E;
    const float c1  = 0.125f * LOG2E;

    // ALiBi reach cap: j-tiles with sl2*(tile start) > 46 only produce
    // exp2 underflow (relative contribution < 2^-27) -> skip them.
    const int jcap   = (int)(46.0f / (sl2 * 64.0f)) + 1;
    const int ntiles = min(qb + 1, jcap);

    bf16x8 qf0 = *(const bf16x8*)(Qh + (size_t)(iw + l15) * 64 + quad * 8);
    bf16x8 qf1 = *(const bf16x8*)(Qh + (size_t)(iw + l15) * 64 + 32 + quad * 8);

    s4 onesf;
    #pragma unroll
    for (int e = 0; e < 4; ++e) onesf[e] = (short)0x3F80;

    // per-lane bias base: -sl2*(quad*4+r); per-subtile only add -sl2*j0s.
    float nb[4];
    #pragma unroll
    for (int r = 0; r < 4; ++r) nb[r] = -sl2 * (float)(quad * 4 + r);

    f32x4 accv[4] = {};
    f32x4 accl = {};

    const int sr = tid >> 2, sc = (tid & 3) * 16;

    uint4 ka0 = *(const uint4*)(Kh + (size_t)sr * 64 + sc);
    uint4 ka1 = *(const uint4*)(Kh + (size_t)sr * 64 + sc + 8);
    uint4 va0 = *(const uint4*)(Vh + (size_t)sr * 2048 + sc);
    uint4 va1 = *(const uint4*)(Vh + (size_t)sr * 2048 + sc + 8);

    auto subtile = [&](int jt, int js, bool masked) {
        const int j0s = jt * 64 + js * 16;
        const float bj = -sl2 * (float)j0s;   // wave-uniform per subtile
        f32x4 sT = {};
        bf16x8 kf0 = *(const bf16x8*)(Ks + (js * 16 + l15) * 72 + quad * 8);
        bf16x8 kf1 = *(const bf16x8*)(Ks + (js * 16 + l15) * 72 + 32 + quad * 8);
        sT = MFMA_16x16x32(kf0, qf0, sT);
        sT = MFMA_16x16x32(kf1, qf1, sT);
        unsigned u[4];
        #pragma unroll
        for (int r = 0; r < 4; ++r) {
            float p = exp2f(fmaf(sT[r], c1, nb[r] + bj));
            if (masked && (j0s + quad * 4 + r) > i_) p = 0.0f;
            u[r] = __builtin_bit_cast(unsigned, p) + 0x8000u;
        }
        uint2 dd = { (u[0] >> 16) | (u[1] & 0xFFFF0000u),
                     (u[2] >> 16) | (u[3] & 0xFFFF0000u) };
        s4 pf = __builtin_bit_cast(s4, dd);
        accl = MFMA16(onesf, pf, accl);
        #pragma unroll
        for (int dt = 0; dt < 4; ++dt) {
            s4 vf = *(const s4*)(Vs + (dt * 16 + l15) * 72 + js * 16 + quad * 4);
            accv[dt] = MFMA16(vf, pf, accv[dt]);
        }
    };

    for (int jt = 0; jt < ntiles; ++jt) {
        __syncthreads();
        *(uint4*)(Ks + sr * 72 + sc)     = ka0;
        *(uint4*)(Ks + sr * 72 + sc + 8) = ka1;
        *(uint4*)(Vs + sr * 72 + sc)     = va0;
        *(uint4*)(Vs + sr * 72 + sc + 8) = va1;
        __syncthreads();
        if (jt + 1 < ntiles) {
            int j0n = (jt + 1) * 64;
            ka0 = *(const uint4*)(Kh + (size_t)(j0n + sr) * 64 + sc);
            ka1 = *(const uint4*)(Kh + (size_t)(j0n + sr) * 64 + sc + 8);
            va0 = *(const uint4*)(Vh + (size_t)sr * 2048 + j0n + sc);
            va1 = *(const uint4*)(Vh + (size_t)sr * 2048 + j0n + sc + 8);
        }
        if (jt < qb) {
            #pragma unroll
            for (int js = 0; js < 4; ++js) subtile(jt, js, false);
        } else {
            for (int js = 0; js < wv; ++js) subtile(jt, js, false);
            subtile(jt, wv, true);
        }
    }

    const float inv = 1.0f / fmaxf(accl[0], 1e-30f);
    const size_t obase = ((size_t)(b * 2048 + i_)) * 1024 + h * 64;
    #pragma unroll
    for (int dt = 0; dt < 4; ++dt) {
        ushort_t pk[4];
        #pragma unroll
        for (int r = 0; r < 4; ++r) pk[r] = f2bf(accv[dt][r] * inv);
        *(ushort2*)(AO + obase + dt * 16 + quad * 4)     = *(ushort2*)&pk[0];
        *(ushort2*)(AO + obase + dt * 16 + quad * 4 + 2) = *(ushort2*)&pk[2];
    }
}

// ---------------- Output projection GEMM + bias, global_load_lds -> FP32 ----------------
__global__ __launch_bounds__(256) void oproj_gemm(
    const ushort_t* __restrict__ A, const ushort_t* __restrict__ WT,
    const ushort_t* __restrict__ bias, float* __restrict__ out)
{
    __shared__ ushort_t As[128 * 32];
    __shared__ ushort_t Bs[128 * 32];

    const int tid  = threadIdx.x;
    const int m0   = blockIdx.y * 128, n0 = blockIdx.x * 128;
    const int lane = tid & 63, wv = tid >> 6;
    const int quad = lane >> 4, l15 = lane & 15;
    const int wm = (wv & 1) * 64, wn = (wv >> 1) * 64;

    const int lrow = lane >> 2;
    const int schk = (lane & 3) ^ ((lane >> 3) & 3);
    const int ra0_ = wv * 16 + lrow;
    ushort_t* aB0 = As + wv * 512;
    ushort_t* aB1 = As + 2048 + wv * 512;
    ushort_t* bB0 = Bs + wv * 512;
    ushort_t* bB1 = Bs + 2048 + wv * 512;
    const int sp = quad ^ ((l15 >> 1) & 3);

    f32x4 acc[4][4] = {};

    for (int kt = 0; kt < 32; ++kt) {
        const int k0 = kt * 32;
        __syncthreads();
        gl_lds16(A  + (size_t)(m0 + ra0_)      * 1024 + k0 + schk * 8, aB0);
        gl_lds16(A  + (size_t)(m0 + 64 + ra0_) * 1024 + k0 + schk * 8, aB1);
        gl_lds16(WT + (size_t)(n0 + ra0_)      * 1024 + k0 + schk * 8, bB0);
        gl_lds16(WT + (size_t)(n0 + 64 + ra0_) * 1024 + k0 + schk * 8, bB1);
        __syncthreads();

        bf16x8 af[4], bfr[4];
        #pragma unroll
        for (int t = 0; t < 4; ++t) {
            af[t]  = *(const bf16x8*)(As + (wm + t * 16 + l15) * 32 + sp * 8);
            bfr[t] = *(const bf16x8*)(Bs + (wn + t * 16 + l15) * 32 + sp * 8);
        }
        #pragma unroll
        for (int mt = 0; mt < 4; ++mt)
            #pragma unroll
            for (int nt = 0; nt < 4; ++nt)
                acc[mt][nt] = MFMA_16x16x32(af[mt], bfr[nt], acc[mt][nt]);
    }

    #pragma unroll
    for (int mt = 0; mt < 4; ++mt) {
        #pragma unroll
        for (int nt = 0; nt < 4; ++nt) {
            #pragma unroll
            for (int r = 0; r < 4; ++r) {
                int m = m0 + wm + mt * 16 + quad * 4 + r;
                int c = n0 + wn + nt * 16 + l15;
                out[(size_t)m * 1024 + c] = acc[mt][nt][r] + bf2f(bias[c]);
            }
        }
    }
}

extern "C" void kernel_launch(void* const* d_in, const int* in_sizes, int n_in,
                              void* d_out, int out_size, void* d_ws, size_t ws_size,
                              hipStream_t stream) {
    const void* X  = d_in[0];
    const void* Wq = d_in[1];
    const void* Wk = d_in[2];
    const void* Wv = d_in[3];
    const void* Wo = d_in[4];
    const void* bo = d_in[5];

    const size_t M = 1024 * 1024;
    ushort_t* ws  = (ushort_t*)d_ws;
    ushort_t* Qb  = ws;
    ushort_t* Kb  = ws + 4 * M;
    ushort_t* Vt  = ws + 8 * M;
    ushort_t* Xc  = ws + 12 * M;    // shared with AO (Xc dead after qkv_gemm)
    ushort_t* AO  = ws + 12 * M;
    ushort_t* WqT = ws + 16 * M;
    ushort_t* WkT = ws + 17 * M;
    ushort_t* WvT = ws + 18 * M;
    ushort_t* WoT = ws + 19 * M;
    ushort_t* boc = ws + 20 * M;
    float* out = (float*)d_out;

    convert_x<<<2049, 256, 0, stream>>>(X, Wq, bo, Xc, boc);
    transpose_w<<<dim3(16, 16, 4), 256, 0, stream>>>(Wq, Wk, Wv, Wo, WqT, WkT, WvT, WoT);
    qkv_gemm<<<dim3(8, 32, 3), 256, 0, stream>>>(Xc, WqT, WkT, WvT, Qb, Kb, Vt);
    attn_kernel<<<1024, 256, 0, stream>>>(Qb, Kb, Vt, AO);
    oproj_gemm<<<dim3(8, 32), 256, 0, stream>>>(AO, WoT, boc, out);
}